// Round 2
// baseline (21394.972 us; speedup 1.0000x reference)
//
#include <hip/hip_runtime.h>
#include <cstdint>

#define B_ 4
#define N_ 16384
#define C_ 64
#define O_ 128
#define S_ 4096
#define K_ 32
#define CK_ 67  // C+3

// ---------------------------------------------------------------------------
// FPS: one block per batch. xyz + running min-dist in registers (16 pts/thr).
// Emits far BEFORE update (matches jax scan), argmax tie-break = lowest index.
// PASSED round 1 bit-exact -- do not change this kernel.
// ---------------------------------------------------------------------------
__launch_bounds__(1024, 1)
__global__ void fps_kernel(const float* __restrict__ xyz,
                           float* __restrict__ new_xyz) {
#pragma clang fp contract(off)
  const int b = blockIdx.x;
  const int tid = threadIdx.x;
  const float* base = xyz + (size_t)b * N_ * 3;
  constexpr int PPT = N_ / 1024;  // 16
  float px[PPT], py[PPT], pz[PPT], dist[PPT];
#pragma unroll
  for (int j = 0; j < PPT; ++j) {
    int p = j * 1024 + tid;
    px[j] = base[p * 3 + 0];
    py[j] = base[p * 3 + 1];
    pz[j] = base[p * 3 + 2];
    dist[j] = 1e10f;
  }
  __shared__ float s_c[3];
  __shared__ float s_rv[16];
  __shared__ int s_ri[16];
  const int lane = tid & 63;
  const int wid = tid >> 6;
  int far = 0;  // meaningful on tid 0 (== wave0 lane0)
  for (int s = 0; s < S_; ++s) {
    if (tid == 0) {
      float cx = base[far * 3 + 0];
      float cy = base[far * 3 + 1];
      float cz = base[far * 3 + 2];
      s_c[0] = cx; s_c[1] = cy; s_c[2] = cz;
      float* o = new_xyz + ((size_t)b * S_ + s) * 3;
      o[0] = cx; o[1] = cy; o[2] = cz;
    }
    __syncthreads();
    const float cx = s_c[0], cy = s_c[1], cz = s_c[2];
    float bv = -1.0f;
    int bi = 0x7fffffff;
#pragma unroll
    for (int j = 0; j < PPT; ++j) {
      float dx = px[j] - cx;
      float dy = py[j] - cy;
      float dz = pz[j] - cz;
      float d = dx * dx + dy * dy + dz * dz;  // contract off: mul,mul,mul,add,add
      float m = fminf(dist[j], d);
      dist[j] = m;
      if (m > bv) { bv = m; bi = j * 1024 + tid; }  // strict > keeps lowest idx
    }
#pragma unroll
    for (int off = 32; off >= 1; off >>= 1) {
      float ov = __shfl_xor(bv, off);
      int oi = __shfl_xor(bi, off);
      if (ov > bv || (ov == bv && oi < bi)) { bv = ov; bi = oi; }
    }
    if (lane == 0) { s_rv[wid] = bv; s_ri[wid] = bi; }
    __syncthreads();
    if (wid == 0) {
      float v = (lane < 16) ? s_rv[lane] : -1.0f;
      int i = (lane < 16) ? s_ri[lane] : 0x7fffffff;
#pragma unroll
      for (int off = 8; off >= 1; off >>= 1) {
        float ov = __shfl_xor(v, off);
        int oi = __shfl_xor(i, off);
        if (ov > v || (ov == v && oi < i)) { v = ov; i = oi; }
      }
      far = i;
    }
  }
}

// ---------------------------------------------------------------------------
// KNN over new_xyz: 256 queries/block, all 4096 candidates + norms in LDS.
// Top-32 by packed u64 key = [monotone(score)|~idx]  (score desc, idx asc).
// Score arithmetic = ascending-k FMA chain (Eigen/rocBLAS style) to match
// both XLA-CPU and XLA-GPU reference rounding:
//   norm  = fma(z,z, fma(y,y, x*x))
//   inner = fma(az,qz, fma(ay,qy, ax*qx))
//   score = (2*inner - qn) - sn          (left-assoc, matches 2.0*i - xx - xxT)
// ---------------------------------------------------------------------------
__launch_bounds__(256, 2)
__global__ void knn_kernel(const float* __restrict__ new_xyz,
                           int* __restrict__ knn_idx) {
  const int b = blockIdx.y;
  const int t = threadIdx.x;
  const int q = blockIdx.x * 256 + t;
  __shared__ float sx[S_], sy[S_], sz[S_], sn[S_];
  const float* nb = new_xyz + (size_t)b * S_ * 3;
  for (int i = t; i < S_; i += 256) {
    float x = nb[i * 3 + 0], y = nb[i * 3 + 1], z = nb[i * 3 + 2];
    sx[i] = x; sy[i] = y; sz[i] = z;
    sn[i] = fmaf(z, z, fmaf(y, y, x * x));
  }
  __syncthreads();
  const float qx = sx[q], qy = sy[q], qz = sz[q], qn = sn[q];
  unsigned long long kv[K_];
#pragma unroll
  for (int j = 0; j < K_; ++j) kv[j] = 0ull;  // below any finite-score key
  for (int i = 0; i < S_; ++i) {
    float inner = fmaf(sz[i], qz, fmaf(sy[i], qy, sx[i] * qx));
    float score = (2.0f * inner - qn) - sn[i];
    unsigned u = __float_as_uint(score);
    u ^= (unsigned)((int)u >> 31) | 0x80000000u;  // monotone float->u32
    unsigned long long nk =
        ((unsigned long long)u << 32) | (unsigned)(~i);
    if (nk > kv[K_ - 1]) {
#pragma unroll
      for (int j = K_ - 1; j >= 1; --j) {
        bool upPrev = nk > kv[j - 1];
        kv[j] = upPrev ? kv[j - 1] : ((nk > kv[j]) ? nk : kv[j]);
      }
      if (nk > kv[0]) kv[0] = nk;
    }
  }
#pragma unroll
  for (int j = 0; j < K_; ++j)
    knn_idx[((size_t)b * S_ + q) * K_ + j] = (int)(~(unsigned)kv[j]);
}

// ---------------------------------------------------------------------------
// Fused gather + [32x67]@[67x128] + rowLN + ReLU + [32x128]@[128x128] + max32.
// One block per (b,s); thread t owns output column t for both layers.
// ---------------------------------------------------------------------------
__launch_bounds__(128)
__global__ void mlp_kernel(const float* __restrict__ xyz,
                           const float* __restrict__ features,
                           const float* __restrict__ new_xyz,
                           const int* __restrict__ knn_idx,
                           const float* __restrict__ W1,
                           const float* __restrict__ b1,
                           const float* __restrict__ gamma,
                           const float* __restrict__ beta,
                           const float* __restrict__ W2,
                           const float* __restrict__ b2,
                           float* __restrict__ out_feat) {
  const int bs = blockIdx.x;
  const int b = bs >> 12;          // S_ = 4096
  const int s = bs & (S_ - 1);
  const int t = threadIdx.x;
  __shared__ float c_lds[K_][CK_ + 1];  // [32][68], col 67 = zero pad
  __shared__ float hT[O_][K_ + 4];      // transposed h' [128][36] (16B-aligned rows)
  __shared__ int s_idx[K_];
  __shared__ float s_part[2][2][K_];
  const float* fb = features + (size_t)b * N_ * C_;
  const float* xb = xyz + (size_t)b * N_ * 3;
  const float* nx = new_xyz + ((size_t)b * S_ + s) * 3;
  if (t < K_) {
    s_idx[t] = knn_idx[((size_t)b * S_ + s) * K_ + t];
    c_lds[t][CK_] = 0.0f;
  }
  __syncthreads();
  const float qx = nx[0], qy = nx[1], qz = nx[2];
  for (int e = t; e < K_ * CK_; e += 128) {
    int r = e / CK_;
    int k = e - r * CK_;
    int nbi = s_idx[r];
    float v;
    if (k < C_) {
      v = fb[(size_t)nbi * C_ + k];
    } else {
      float coord = xb[nbi * 3 + (k - C_)];
      float qq = (k == C_) ? qx : ((k == C_ + 1) ? qy : qz);
      v = coord - qq;
    }
    c_lds[r][k] = v;
  }
  __syncthreads();

  // GEMM1: h[r] = combined[r,:] . W1[:,t] + b1[t]
  float w1c[CK_ + 1];
#pragma unroll
  for (int k = 0; k < CK_; ++k) w1c[k] = W1[k * O_ + t];
  w1c[CK_] = 0.0f;
  const float bb1 = b1[t], gm = gamma[t], bt = beta[t];
  float h[K_];
#pragma unroll
  for (int r = 0; r < K_; ++r) {
    float acc = 0.0f;
#pragma unroll
    for (int k4 = 0; k4 < (CK_ + 1) / 4; ++k4) {
      float4 cv = *reinterpret_cast<const float4*>(&c_lds[r][k4 * 4]);
      acc = fmaf(cv.x, w1c[k4 * 4 + 0], acc);
      acc = fmaf(cv.y, w1c[k4 * 4 + 1], acc);
      acc = fmaf(cv.z, w1c[k4 * 4 + 2], acc);
      acc = fmaf(cv.w, w1c[k4 * 4 + 3], acc);
    }
    h[r] = acc + bb1;
  }

  // LayerNorm over the 128 columns (cross-thread), then ReLU, store transposed.
  const int lane = t & 63, wv = t >> 6;
#pragma unroll
  for (int r = 0; r < K_; ++r) {
    float s1 = h[r];
    float s2 = h[r] * h[r];
#pragma unroll
    for (int off = 32; off >= 1; off >>= 1) {
      s1 += __shfl_xor(s1, off);
      s2 += __shfl_xor(s2, off);
    }
    if (lane == 0) { s_part[wv][0][r] = s1; s_part[wv][1][r] = s2; }
  }
  __syncthreads();
#pragma unroll
  for (int r = 0; r < K_; ++r) {
    float s1 = s_part[0][0][r] + s_part[1][0][r];
    float s2 = s_part[0][1][r] + s_part[1][1][r];
    float mu = s1 * (1.0f / 128.0f);
    float va = fmaf(mu, -mu, s2 * (1.0f / 128.0f));
    float rs = rsqrtf(va + 1e-5f);
    float hv = fmaf((h[r] - mu) * rs, gm, bt);
    hT[t][r] = fmaxf(hv, 0.0f);
  }
  __syncthreads();

  // GEMM2 + max over 32 rows: out[t] = max_r( h'[r,:] . W2[:,t] ) + b2[t]
  float acc[K_];
#pragma unroll
  for (int r = 0; r < K_; ++r) acc[r] = 0.0f;
#pragma unroll 4
  for (int k = 0; k < O_; ++k) {
    float w = W2[k * O_ + t];
#pragma unroll
    for (int r4 = 0; r4 < K_ / 4; ++r4) {
      float4 hv = *reinterpret_cast<const float4*>(&hT[k][r4 * 4]);
      acc[r4 * 4 + 0] = fmaf(hv.x, w, acc[r4 * 4 + 0]);
      acc[r4 * 4 + 1] = fmaf(hv.y, w, acc[r4 * 4 + 1]);
      acc[r4 * 4 + 2] = fmaf(hv.z, w, acc[r4 * 4 + 2]);
      acc[r4 * 4 + 3] = fmaf(hv.w, w, acc[r4 * 4 + 3]);
    }
  }
  float best = acc[0];
#pragma unroll
  for (int r = 1; r < K_; ++r) best = fmaxf(best, acc[r]);
  out_feat[((size_t)b * S_ + s) * O_ + t] = best + b2[t];
}

extern "C" void kernel_launch(void* const* d_in, const int* in_sizes, int n_in,
                              void* d_out, int out_size, void* d_ws, size_t ws_size,
                              hipStream_t stream) {
  const float* xyz      = (const float*)d_in[0];
  const float* features = (const float*)d_in[1];
  const float* W1       = (const float*)d_in[2];
  const float* b1       = (const float*)d_in[3];
  const float* gamma    = (const float*)d_in[4];
  const float* beta     = (const float*)d_in[5];
  const float* W2       = (const float*)d_in[6];
  const float* b2       = (const float*)d_in[7];

  float* out      = (float*)d_out;
  float* new_xyz  = out;                          // [4,4096,3]
  float* new_feat = out + (size_t)B_ * S_ * 3;    // [4,4096,128]
  int* knn_idx = (int*)d_ws;                      // [4,4096,32]

  fps_kernel<<<B_, 1024, 0, stream>>>(xyz, new_xyz);
  knn_kernel<<<dim3(S_ / 256, B_), 256, 0, stream>>>(new_xyz, knn_idx);
  mlp_kernel<<<B_ * S_, 128, 0, stream>>>(xyz, features, new_xyz, knn_idx,
                                          W1, b1, gamma, beta, W2, b2, new_feat);
}

// Round 3
// 9785.220 us; speedup vs baseline: 2.1865x; 2.1865x over previous
//
#include <hip/hip_runtime.h>
#include <cstdint>

#define B_ 4
#define N_ 16384
#define C_ 64
#define O_ 128
#define S_ 4096
#define K_ 32
#define CK_ 67  // C+3

// ---------------------------------------------------------------------------
// FPS v2: one block/batch, 512 threads x 32 pts. One barrier per iteration.
// Distance formula BIT-IDENTICAL to round-1/2 (passed): contract(off),
// dx*dx + dy*dy + dz*dz, fminf, strict-> argmax (lowest index on ties).
// Cross-thread argmax via packed u64 key (dist_bits<<32 | ~idx), valid since
// all dists >= 0. Winner coords re-loaded via uniform (scalar) global load.
// ---------------------------------------------------------------------------
__launch_bounds__(512, 2)
__global__ void fps_kernel(const float* __restrict__ xyz,
                           float* __restrict__ new_xyz) {
#pragma clang fp contract(off)
  const int b = blockIdx.x;
  const int t = threadIdx.x;
  const float* base = xyz + (size_t)b * N_ * 3;
  constexpr int PPT = N_ / 512;  // 32
  float px[PPT], py[PPT], pz[PPT], dist[PPT];
#pragma unroll
  for (int j = 0; j < PPT; ++j) {
    int p = j * 512 + t;
    px[j] = base[p * 3 + 0];
    py[j] = base[p * 3 + 1];
    pz[j] = base[p * 3 + 2];
    dist[j] = 1e10f;
  }
  __shared__ unsigned long long s_part[2][8];
  const int lane = t & 63;
  const int wid = t >> 6;
  float fx = base[0], fy = base[1], fz = base[2];  // far = 0 initially
  for (int s = 0; s < S_; ++s) {
    if (t == 0) {
      float* o = new_xyz + ((size_t)b * S_ + s) * 3;
      o[0] = fx; o[1] = fy; o[2] = fz;
    }
    float bv = -1.0f;
    int bi = 0;
#pragma unroll
    for (int j = 0; j < PPT; ++j) {
      float dx = px[j] - fx;
      float dy = py[j] - fy;
      float dz = pz[j] - fz;
      float d = dx * dx + dy * dy + dz * dz;
      float m = fminf(dist[j], d);
      dist[j] = m;
      if (m > bv) { bv = m; bi = j * 512 + t; }
    }
    // bv >= 0 here -> float bits are monotone as u32.
    unsigned long long key =
        ((unsigned long long)__float_as_uint(bv) << 32) | (unsigned)(~bi);
#pragma unroll
    for (int off = 1; off <= 32; off <<= 1) {
      unsigned long long ok = __shfl_xor(key, off);
      if (ok > key) key = ok;
    }
    const int buf = s & 1;
    if (lane == 0) s_part[buf][wid] = key;
    __syncthreads();
    unsigned long long kb = s_part[buf][0];
#pragma unroll
    for (int w = 1; w < 8; ++w) {
      unsigned long long ok = s_part[buf][w];
      if (ok > kb) kb = ok;
    }
    const int pw = (int)(~(unsigned)kb);  // uniform across block
    fx = base[pw * 3 + 0];
    fy = base[pw * 3 + 1];
    fz = base[pw * 3 + 2];
  }
}

// ---------------------------------------------------------------------------
// KNN over new_xyz (UNCHANGED from round 2 -- passed, do not touch).
// ---------------------------------------------------------------------------
__launch_bounds__(256, 2)
__global__ void knn_kernel(const float* __restrict__ new_xyz,
                           int* __restrict__ knn_idx) {
  const int b = blockIdx.y;
  const int t = threadIdx.x;
  const int q = blockIdx.x * 256 + t;
  __shared__ float sx[S_], sy[S_], sz[S_], sn[S_];
  const float* nb = new_xyz + (size_t)b * S_ * 3;
  for (int i = t; i < S_; i += 256) {
    float x = nb[i * 3 + 0], y = nb[i * 3 + 1], z = nb[i * 3 + 2];
    sx[i] = x; sy[i] = y; sz[i] = z;
    sn[i] = fmaf(z, z, fmaf(y, y, x * x));
  }
  __syncthreads();
  const float qx = sx[q], qy = sy[q], qz = sz[q], qn = sn[q];
  unsigned long long kv[K_];
#pragma unroll
  for (int j = 0; j < K_; ++j) kv[j] = 0ull;
  for (int i = 0; i < S_; ++i) {
    float inner = fmaf(sz[i], qz, fmaf(sy[i], qy, sx[i] * qx));
    float score = (2.0f * inner - qn) - sn[i];
    unsigned u = __float_as_uint(score);
    u ^= (unsigned)((int)u >> 31) | 0x80000000u;
    unsigned long long nk = ((unsigned long long)u << 32) | (unsigned)(~i);
    if (nk > kv[K_ - 1]) {
#pragma unroll
      for (int j = K_ - 1; j >= 1; --j) {
        bool upPrev = nk > kv[j - 1];
        kv[j] = upPrev ? kv[j - 1] : ((nk > kv[j]) ? nk : kv[j]);
      }
      if (nk > kv[0]) kv[0] = nk;
    }
  }
#pragma unroll
  for (int j = 0; j < K_; ++j)
    knn_idx[((size_t)b * S_ + q) * K_ + j] = (int)(~(unsigned)kv[j]);
}

// ---------------------------------------------------------------------------
// MLP v2: 256 blocks x 256 threads; W1^T/W2^T staged in LDS once per block;
// 64 s-values per block; 4x4 register tiles per GEMM (no spills).
// thread = (g = t>>5 rowgroup: rows 4g..4g+3, cg = t&31: cols cg+32j).
// ---------------------------------------------------------------------------
#define W1S 76   // 67 data + zero pad, stride dwords (16B aligned, conflict-lite)
#define W2S 132
#define CLS 72
#define HPS 132

__launch_bounds__(256, 1)
__global__ void mlp_kernel(const float* __restrict__ xyz,
                           const float* __restrict__ features,
                           const float* __restrict__ new_xyz,
                           const int* __restrict__ knn_idx,
                           const float* __restrict__ W1,
                           const float* __restrict__ b1,
                           const float* __restrict__ gamma,
                           const float* __restrict__ beta,
                           const float* __restrict__ W2,
                           const float* __restrict__ b2,
                           float* __restrict__ out_feat) {
  __shared__ float w1T[O_][W1S];    // 38.9 KB  [col][k]
  __shared__ float w2T[O_][W2S];    // 67.6 KB  [col][k]
  __shared__ float c_l[K_][CLS];    //  9.2 KB  combined [row][k]
  __shared__ float hp[K_][HPS];     // 16.9 KB  h' [row][k]
  __shared__ float pmaxl[8][O_];    //  4.1 KB

  const int t = threadIdx.x;
  const int g = t >> 5;    // 0..7
  const int cg = t & 31;   // 0..31

  // ---- stage W1^T, W2^T (once per block) ----
  for (int e = t; e < CK_ * O_; e += 256) {
    int k = e >> 7, c = e & (O_ - 1);
    w1T[c][k] = W1[e];
  }
  if (t < O_) {
#pragma unroll
    for (int k = CK_; k < 68; ++k) w1T[t][k] = 0.0f;
  }
  for (int e = t; e < O_ * O_; e += 256) {
    int k = e >> 7, c = e & (O_ - 1);
    w2T[c][k] = W2[e];
  }
  // per-thread epilogue constants for its 4 columns
  float bb1[4], gm[4], bt[4], bb2 = 0.0f;
#pragma unroll
  for (int j = 0; j < 4; ++j) {
    bb1[j] = b1[cg + 32 * j];
    gm[j] = gamma[cg + 32 * j];
    bt[j] = beta[cg + 32 * j];
  }
  if (t < O_) bb2 = b2[t];

  const int bs0 = blockIdx.x * 64;
  const int b = bs0 >> 12;
  const float* fb = features + (size_t)b * N_ * C_;
  const float* xb = xyz + (size_t)b * N_ * 3;

  __syncthreads();  // weights staged

  for (int is = 0; is < 64; ++is) {
    const int bs = bs0 + is;
    const float qx = new_xyz[(size_t)bs * 3 + 0];
    const float qy = new_xyz[(size_t)bs * 3 + 1];
    const float qz = new_xyz[(size_t)bs * 3 + 2];

    // ---- gather combined[32][67] (+ zero pad col 67) ----
    for (int e = t; e < K_ * 68; e += 256) {
      int r = e >> 6;           // e / 64? no: 68 per row -> use div
      r = e / 68;
      int k = e - r * 68;
      int nbi = knn_idx[(size_t)bs * K_ + r];
      float v;
      if (k < C_) {
        v = fb[(size_t)nbi * C_ + k];
      } else if (k < CK_) {
        float coord = xb[nbi * 3 + (k - C_)];
        float qq = (k == C_) ? qx : ((k == C_ + 1) ? qy : qz);
        v = coord - qq;
      } else {
        v = 0.0f;
      }
      c_l[r][k] = v;
    }
    __syncthreads();  // (A) gather done

    // ---- GEMM1: h[i][j] = combined[4g+i,:] . W1[:, cg+32j] ----
    float h[4][4];
#pragma unroll
    for (int i = 0; i < 4; ++i)
#pragma unroll
      for (int j = 0; j < 4; ++j) h[i][j] = 0.0f;
#pragma unroll
    for (int kc = 0; kc < 17; ++kc) {
      float4 w[4], a[4];
#pragma unroll
      for (int j = 0; j < 4; ++j)
        w[j] = *reinterpret_cast<const float4*>(&w1T[cg + 32 * j][kc * 4]);
#pragma unroll
      for (int i = 0; i < 4; ++i)
        a[i] = *reinterpret_cast<const float4*>(&c_l[4 * g + i][kc * 4]);
#pragma unroll
      for (int i = 0; i < 4; ++i)
#pragma unroll
        for (int j = 0; j < 4; ++j) {
          h[i][j] = fmaf(a[i].x, w[j].x, h[i][j]);
          h[i][j] = fmaf(a[i].y, w[j].y, h[i][j]);
          h[i][j] = fmaf(a[i].z, w[j].z, h[i][j]);
          h[i][j] = fmaf(a[i].w, w[j].w, h[i][j]);
        }
    }
#pragma unroll
    for (int i = 0; i < 4; ++i)
#pragma unroll
      for (int j = 0; j < 4; ++j) h[i][j] += bb1[j];

    // ---- LayerNorm over 128 cols (half-wave = the 32 cg's of one g) ----
#pragma unroll
    for (int i = 0; i < 4; ++i) {
      float s1 = (h[i][0] + h[i][1]) + (h[i][2] + h[i][3]);
      float s2 = ((h[i][0] * h[i][0] + h[i][1] * h[i][1]) +
                  (h[i][2] * h[i][2] + h[i][3] * h[i][3]));
#pragma unroll
      for (int off = 1; off <= 16; off <<= 1) {
        s1 += __shfl_xor(s1, off);
        s2 += __shfl_xor(s2, off);
      }
      float mu = s1 * (1.0f / 128.0f);
      float va = fmaf(mu, -mu, s2 * (1.0f / 128.0f));
      float rs = rsqrtf(va + 1e-5f);
#pragma unroll
      for (int j = 0; j < 4; ++j) {
        float hv = fmaf((h[i][j] - mu) * rs, gm[j], bt[j]);
        hp[4 * g + i][cg + 32 * j] = fmaxf(hv, 0.0f);
      }
    }
    __syncthreads();  // (B) hp ready

    // ---- GEMM2: acc[i][j] = hp[4g+i,:] . W2[:, cg+32j] ----
    float acc[4][4];
#pragma unroll
    for (int i = 0; i < 4; ++i)
#pragma unroll
      for (int j = 0; j < 4; ++j) acc[i][j] = 0.0f;
#pragma unroll 8
    for (int kc = 0; kc < 32; ++kc) {
      float4 w[4], a[4];
#pragma unroll
      for (int j = 0; j < 4; ++j)
        w[j] = *reinterpret_cast<const float4*>(&w2T[cg + 32 * j][kc * 4]);
#pragma unroll
      for (int i = 0; i < 4; ++i)
        a[i] = *reinterpret_cast<const float4*>(&hp[4 * g + i][kc * 4]);
#pragma unroll
      for (int i = 0; i < 4; ++i)
#pragma unroll
        for (int j = 0; j < 4; ++j) {
          acc[i][j] = fmaf(a[i].x, w[j].x, acc[i][j]);
          acc[i][j] = fmaf(a[i].y, w[j].y, acc[i][j]);
          acc[i][j] = fmaf(a[i].z, w[j].z, acc[i][j]);
          acc[i][j] = fmaf(a[i].w, w[j].w, acc[i][j]);
        }
    }
#pragma unroll
    for (int j = 0; j < 4; ++j) {
      float pm = fmaxf(fmaxf(acc[0][j], acc[1][j]), fmaxf(acc[2][j], acc[3][j]));
      pmaxl[g][cg + 32 * j] = pm;
    }
    __syncthreads();  // (C) partial maxes ready

    if (t < O_) {
      float m = pmaxl[0][t];
#pragma unroll
      for (int w = 1; w < 8; ++w) m = fmaxf(m, pmaxl[w][t]);
      out_feat[(size_t)bs * O_ + t] = m + bb2;
    }
    __syncthreads();  // protect c_l/hp/pmaxl for next iteration
  }
}

extern "C" void kernel_launch(void* const* d_in, const int* in_sizes, int n_in,
                              void* d_out, int out_size, void* d_ws, size_t ws_size,
                              hipStream_t stream) {
  const float* xyz      = (const float*)d_in[0];
  const float* features = (const float*)d_in[1];
  const float* W1       = (const float*)d_in[2];
  const float* b1       = (const float*)d_in[3];
  const float* gamma    = (const float*)d_in[4];
  const float* beta     = (const float*)d_in[5];
  const float* W2       = (const float*)d_in[6];
  const float* b2       = (const float*)d_in[7];

  float* out      = (float*)d_out;
  float* new_xyz  = out;                          // [4,4096,3]
  float* new_feat = out + (size_t)B_ * S_ * 3;    // [4,4096,128]
  int* knn_idx = (int*)d_ws;                      // [4,4096,32]

  fps_kernel<<<B_, 512, 0, stream>>>(xyz, new_xyz);
  knn_kernel<<<dim3(S_ / 256, B_), 256, 0, stream>>>(new_xyz, knn_idx);
  mlp_kernel<<<B_ * S_ / 64, 256, 0, stream>>>(xyz, features, new_xyz, knn_idx,
                                               W1, b1, gamma, beta, W2, b2,
                                               new_feat);
}